// Round 2
// baseline (4742.029 us; speedup 1.0000x reference)
//
#include <hip/hip_runtime.h>
#include <math.h>

// Problem constants (fixed by setup_inputs)
#define BQ    1024      // queries
#define NB    131072    // blobs
#define DS    64        // spatial dim
#define DF    256       // feature dim
#define KSEL  16        // top-k

// Score kernel tiling
#define QT    64        // queries per tile (grid.y = 16)
#define BC    64        // blobs per chunk
#define KDIM  128       // 2*DS  ([q^2 ; -2q] x [iv ; mu*iv])
#define LDT   68        // padded LDS leading dim (16B-aligned rows)
#define PCH   32        // chunk-blocks per query tile (grid.x)
#define NCHUNK (NB / BC)        // 2048
#define CPQ   (PCH * KSEL)      // 512 candidates per query
#define CAP   320               // LDS candidate buffer entries

__device__ __forceinline__ unsigned map_f32(float s) {
    // order-preserving f32 -> u32 (handles negatives: log-scores are < 0)
    unsigned u = __float_as_uint(s);
    return (u & 0x80000000u) ? ~u : (u | 0x80000000u);
}

__global__ __launch_bounds__(256, 2)
void score_topk_kernel(const float* __restrict__ query,
                       const float* __restrict__ mu,
                       const float* __restrict__ log_var,
                       const float* __restrict__ raw_alpha,
                       const float* __restrict__ log_tau_p,
                       unsigned long long* __restrict__ cand)
{
    __shared__ float At[KDIM][LDT];   // [0:64)=q^2, [64:128)=-2q  (k-major)
    __shared__ float Bt[KDIM][LDT];   // [0:64)=iv,  [64:128)=mu*iv (k-major)
    __shared__ float Sm2[BC];
    __shared__ float Sla[BC];         // log(sigmoid(raw_alpha))
    __shared__ float top_s[QT][KSEL]; // sorted desc, log-domain
    __shared__ int   top_i[QT][KSEL];
    __shared__ float cutoff[QT];
    __shared__ unsigned long long buf[CAP];
    __shared__ int buf_count;

    const int tid   = threadIdx.x;
    const int qbase = blockIdx.y * QT;

    const float nhit = -0.5f * expf(-log_tau_p[0]);   // -0.5 / tau

    // ---- stage queries -> At (once per block) ----
    #pragma unroll
    for (int it = 0; it < (QT * DS) / 256; ++it) {
        int idx = tid + it * 256;
        int ql = idx >> 6;
        int d  = idx & 63;
        float v = query[(size_t)(qbase + ql) * DS + d];
        At[d][ql]      = v * v;
        At[d + DS][ql] = -2.0f * v;
    }
    for (int idx = tid; idx < QT * KSEL; idx += 256) {
        (&top_s[0][0])[idx] = -INFINITY;
        (&top_i[0][0])[idx] = 0x7FFFFFFF;
    }
    if (tid < QT) cutoff[tid] = -INFINITY;

    const int tx = tid & 15;    // blob group  (4 blobs)
    const int ty = tid >> 4;    // query group (4 queries)

    for (int c = blockIdx.x; c < NCHUNK; c += PCH) {
        const int nbase = c * BC;
        __syncthreads();   // previous chunk fully done; Bt safe to overwrite

        // ---- stage blob chunk: iv, mu*iv, m2, log-alpha ----
        #pragma unroll
        for (int it = 0; it < (BC * DS) / 256; ++it) {
            int idx = tid + it * 256;
            int nl = idx >> 6;          // wave-uniform
            int d  = idx & 63;
            size_t g = (size_t)(nbase + nl) * DS + d;
            float m  = mu[g];
            float iv = expf(-log_var[g]);
            float mv = m * iv;
            Bt[d][nl]      = iv;
            Bt[d + DS][nl] = mv;
            float p = m * mv;           // mu^2 * iv
            #pragma unroll
            for (int off = 32; off > 0; off >>= 1) p += __shfl_down(p, off);
            if (d == 0) Sm2[nl] = p;
        }
        if (tid < BC)
            Sla[tid] = -log1pf(expf(-raw_alpha[nbase + tid]));  // log sigmoid
        if (tid == 0) buf_count = 0;
        __syncthreads();

        // ---- 64x64 tile, 4x4 register tile, K=128 ----
        float acc[4][4];
        #pragma unroll
        for (int i = 0; i < 4; ++i)
            #pragma unroll
            for (int j = 0; j < 4; ++j) acc[i][j] = 0.0f;

        #pragma unroll 8
        for (int kk = 0; kk < KDIM; ++kk) {
            float4 av = *reinterpret_cast<const float4*>(&At[kk][ty << 2]);
            float4 bv = *reinterpret_cast<const float4*>(&Bt[kk][tx << 2]);
            float a4[4] = {av.x, av.y, av.z, av.w};
            float b4[4] = {bv.x, bv.y, bv.z, bv.w};
            #pragma unroll
            for (int i = 0; i < 4; ++i)
                #pragma unroll
                for (int j = 0; j < 4; ++j)
                    acc[i][j] += a4[i] * b4[j];
        }

        // ---- epilogue in LOG domain: logscore = nhit*(mahal) + log_alpha ----
        float sc[4][4];
        float m2v[4], lav[4];
        #pragma unroll
        for (int j = 0; j < 4; ++j) {
            m2v[j] = Sm2[(tx << 2) + j];
            lav[j] = Sla[(tx << 2) + j];
        }
        #pragma unroll
        for (int i = 0; i < 4; ++i)
            #pragma unroll
            for (int j = 0; j < 4; ++j)
                sc[i][j] = nhit * (acc[i][j] + m2v[j]) + lav[j];

        // ---- filtered candidate append + parallel owner insertion ----
        unsigned mask = 0;      // which of my 16 scores already appended
        for (;;) {
            #pragma unroll
            for (int i = 0; i < 4; ++i) {
                float cut = cutoff[(ty << 2) + i];
                #pragma unroll
                for (int j = 0; j < 4; ++j) {
                    unsigned bit = 1u << (i * 4 + j);
                    if (!(mask & bit) && sc[i][j] > cut) {
                        int pos = atomicAdd(&buf_count, 1);
                        if (pos < CAP) {
                            unsigned qi   = (ty << 2) + i;
                            unsigned gidx = (unsigned)(nbase + (tx << 2) + j);
                            buf[pos] = ((unsigned long long)__float_as_uint(sc[i][j]) << 32)
                                     | ((unsigned long long)qi << 24) | gidx;
                            mask |= bit;
                        }
                    }
                }
            }
            __syncthreads();                    // appends done
            int cnt = buf_count;                // uniform (no writes until B2)
            if (cnt == 0) break;                // common steady-state path
            __syncthreads();                    // all threads have read cnt
            int lim = cnt < CAP ? cnt : CAP;
            if (tid == 0 && cnt > CAP) buf_count = 0;   // reset for re-run
            if (tid < QT) {
                int q = tid;
                for (int e = 0; e < lim; ++e) {
                    unsigned long long k = buf[e];   // broadcast read
                    if ((int)((k >> 24) & 0xFF) == q) {
                        float s = __uint_as_float((unsigned)(k >> 32));
                        if (s > top_s[q][KSEL - 1]) {
                            int p = KSEL - 1;
                            while (p > 0 && top_s[q][p - 1] < s) {
                                top_s[q][p] = top_s[q][p - 1];
                                top_i[q][p] = top_i[q][p - 1];
                                --p;
                            }
                            top_s[q][p] = s;
                            top_i[q][p] = (int)(k & 0xFFFFFF);
                        }
                    }
                }
                cutoff[q] = top_s[q][KSEL - 1];
            }
            __syncthreads();                    // processing + reset visible
            if (cnt <= CAP) break;
        }
    }
    __syncthreads();

    // ---- write candidates as order-preserving packed keys ----
    for (int idx = tid; idx < QT * KSEL; idx += 256) {
        int ql = idx >> 4, sl = idx & 15;
        unsigned ms  = map_f32(top_s[ql][sl]);
        unsigned inv = 0xFFFFFFFFu - (unsigned)top_i[ql][sl];   // lower idx wins ties
        cand[(size_t)(qbase + ql) * CPQ + blockIdx.x * KSEL + sl] =
            ((unsigned long long)ms << 32) | inv;
    }
}

__global__ __launch_bounds__(256)
void merge_composite_kernel(const float* __restrict__ query,
                            const float* __restrict__ mu,
                            const float* __restrict__ log_var,
                            const float* __restrict__ raw_alpha,
                            const float* __restrict__ features,
                            const float* __restrict__ log_tau_p,
                            const unsigned long long* __restrict__ cand,
                            float* __restrict__ out)
{
    const int q   = blockIdx.x;
    const int tid = threadIdx.x;
    const int wv = tid >> 6, lane = tid & 63;

    __shared__ unsigned long long wmax[4];
    __shared__ int   sel[KSEL];
    __shared__ float w_sh[KSEL];
    __shared__ float mah[KSEL];
    __shared__ float alp[KSEL];

    // 512 candidate keys live in registers (2 per thread)
    unsigned long long k0 = cand[(size_t)q * CPQ + tid];
    unsigned long long k1 = cand[(size_t)q * CPQ + tid + 256];

    for (int r = 0; r < KSEL; ++r) {
        unsigned long long m = k0 > k1 ? k0 : k1;
        #pragma unroll
        for (int off = 32; off > 0; off >>= 1) {
            unsigned hi = __shfl_xor((unsigned)(m >> 32), off);
            unsigned lo = __shfl_xor((unsigned)(m & 0xFFFFFFFFu), off);
            unsigned long long o = ((unsigned long long)hi << 32) | lo;
            if (o > m) m = o;
        }
        if (lane == 0) wmax[wv] = m;
        __syncthreads();
        unsigned long long w = wmax[0];
        #pragma unroll
        for (int t = 1; t < 4; ++t) if (wmax[t] > w) w = wmax[t];
        if (tid == 0)
            sel[r] = (int)(0xFFFFFFFFu - (unsigned)(w & 0xFFFFFFFFull));
        if (k0 == w) k0 = 0ull;     // keys unique -> exactly one removal
        if (k1 == w) k1 = 0ull;
        __syncthreads();            // protects wmax for next round; sel visible
    }

    // exact mahal per selected blob (direct gathered form, like reference)
    for (int r = wv; r < KSEL; r += 4) {
        int bi = sel[r];
        float qd = query[(size_t)q * DS + lane];
        float mv = mu[(size_t)bi * DS + lane];
        float d  = qd - mv;
        float t  = d * d * expf(-log_var[(size_t)bi * DS + lane]);
        #pragma unroll
        for (int off = 32; off > 0; off >>= 1) t += __shfl_down(t, off);
        if (lane == 0) {
            mah[r] = t;
            alp[r] = 1.0f / (1.0f + expf(-raw_alpha[bi]));
        }
    }
    __syncthreads();

    // serial log-space compositing (16 steps)
    if (tid == 0) {
        float tau = expf(log_tau_p[0]);
        float cap = 0.3f / 16.0f;          // T_MAX / k
        float logT = 0.0f;
        for (int r = 0; r < KSEL; ++r) {
            float K   = expf(-0.5f * mah[r] / tau);
            float eff = fminf(alp[r] * K, cap);
            w_sh[r]   = eff * expf(logT);
            logT     += log1pf(-fminf(eff, 1.0f - 1e-6f));
        }
        out[(size_t)BQ * DF + q] = expf(logT);   // t_residual
    }
    __syncthreads();

    // weighted feature sum (coalesced)
    {
        float a = 0.0f;
        #pragma unroll
        for (int r = 0; r < KSEL; ++r)
            a += w_sh[r] * features[(size_t)sel[r] * DF + tid];
        out[(size_t)q * DF + tid] = a;
    }
}

extern "C" void kernel_launch(void* const* d_in, const int* in_sizes, int n_in,
                              void* d_out, int out_size, void* d_ws, size_t ws_size,
                              hipStream_t stream)
{
    (void)in_sizes; (void)n_in; (void)out_size; (void)ws_size;
    const float* query     = (const float*)d_in[0];
    const float* mu        = (const float*)d_in[1];
    const float* log_var   = (const float*)d_in[2];
    const float* raw_alpha = (const float*)d_in[3];
    const float* features  = (const float*)d_in[4];
    const float* log_tau   = (const float*)d_in[5];
    float* out = (float*)d_out;

    unsigned long long* cand = (unsigned long long*)d_ws;   // [BQ][CPQ] u64 = 4 MB

    dim3 g2(PCH, BQ / QT);
    score_topk_kernel<<<g2, 256, 0, stream>>>(query, mu, log_var, raw_alpha,
                                              log_tau, cand);
    merge_composite_kernel<<<BQ, 256, 0, stream>>>(query, mu, log_var, raw_alpha,
                                                   features, log_tau, cand, out);
}

// Round 3
// 721.245 us; speedup vs baseline: 6.5748x; 6.5748x over previous
//
#include <hip/hip_runtime.h>
#include <math.h>

// ---------------- problem constants ----------------
#define BQ    1024
#define NB    131072
#define DS    64
#define DF    256
#define KSEL  16

// ---------------- score kernel tiling ----------------
#define QT    128        // queries per block (4 waves x 32)
#define BC    64         // blobs per chunk
#define KDIM  128        // concat [q^2 ; -2q] x [iv ; mu*iv]
#define PCH   64         // chunk stripes (grid.x)
#define NCHUNK (NB / BC)             // 2048
#define CHUNKS_PER_BLK (NCHUNK/PCH)  // 32
#define CPQ   (PCH * KSEL)           // 1024 candidates per query
#define SLD   68                     // Stile leading dim (floats, 272B rows, 16B-aligned)

// Bprep layout per chunk: [split(2)][ntile(4)][kstep(4)][lane(64)][16B] = 32 KB
#define CH_BYTES   32768
#define SPLIT_OFF  16384

typedef __bf16 bf16x8 __attribute__((ext_vector_type(8)));
typedef float  f32x4  __attribute__((ext_vector_type(4)));
typedef unsigned long long u64;

__device__ __forceinline__ unsigned map_f32(float s) {
    unsigned u = __float_as_uint(s);
    return (u & 0x80000000u) ? ~u : (u | 0x80000000u);
}

__device__ __forceinline__ void async_cp16(const void* g, void* l) {
    __builtin_amdgcn_global_load_lds(
        (const __attribute__((address_space(1))) unsigned int*)g,
        (__attribute__((address_space(3))) unsigned int*)l, 16, 0, 0);
}

// ---------------- preprocess: B panels -> fragment-ordered bf16 hi/lo ----------------
__global__ __launch_bounds__(256)
void prep_b_kernel(const float* __restrict__ mu,
                   const float* __restrict__ log_var,
                   char* __restrict__ bprep)
{
    int gid  = blockIdx.x * 256 + threadIdx.x;   // 2^21 threads
    int lane = gid & 63;
    int ks   = (gid >> 6) & 3;
    int nt   = (gid >> 8) & 3;
    int c    = gid >> 10;

    int blob = c * BC + nt * 16 + (lane & 15);
    int kq   = ks * 32 + (lane >> 4) * 8;        // k of first element
    int d0   = kq & 63;
    bool lin = kq >= 64;                         // false: iv row; true: mu*iv row

    const float* mrow = mu      + (size_t)blob * DS + d0;
    const float* vrow = log_var + (size_t)blob * DS + d0;

    bf16x8 h, l;
    #pragma unroll
    for (int j = 0; j < 8; ++j) {
        float m  = mrow[j];
        float iv = expf(-vrow[j]);
        float x  = lin ? (m * iv) : iv;
        __bf16 hb = (__bf16)x;
        h[j] = hb;
        l[j] = (__bf16)(x - (float)hb);
    }
    size_t base = (size_t)c * CH_BYTES + nt * 4096 + ks * 1024 + lane * 16;
    *(bf16x8*)(bprep + base)             = h;
    *(bf16x8*)(bprep + base + SPLIT_OFF) = l;
}

// ---------------- preprocess: m2 (= sum mu^2*iv) and log-sigmoid(alpha) ----------------
__global__ __launch_bounds__(256)
void prep_m_kernel(const float* __restrict__ mu,
                   const float* __restrict__ log_var,
                   const float* __restrict__ raw_alpha,
                   float* __restrict__ m2la)       // [NB][2]
{
    int wv   = threadIdx.x >> 6;
    int lane = threadIdx.x & 63;
    int blob = blockIdx.x * 4 + wv;
    size_t g = (size_t)blob * DS + lane;
    float m  = mu[g];
    float iv = expf(-log_var[g]);
    float p  = m * m * iv;
    #pragma unroll
    for (int off = 32; off > 0; off >>= 1) p += __shfl_down(p, off);
    if (lane == 0) {
        m2la[blob * 2]     = p;
        m2la[blob * 2 + 1] = -log1pf(expf(-raw_alpha[blob]));  // log sigmoid
    }
}

// ---------------- register top-16 insertion (unsorted + min cutoff) ----------------
__device__ __forceinline__ void ins16(float (&ts)[16], int (&ti)[16],
                                      float& cut, float s, int idx)
{
    int am = 0; float mv = ts[0];
    #pragma unroll
    for (int i = 1; i < 16; ++i) { bool b = ts[i] < mv; mv = b ? ts[i] : mv; am = b ? i : am; }
    #pragma unroll
    for (int i = 0; i < 16; ++i) { bool b = (i == am); ts[i] = b ? s : ts[i]; ti[i] = b ? idx : ti[i]; }
    float nm = ts[0];
    #pragma unroll
    for (int i = 1; i < 16; ++i) nm = fminf(nm, ts[i]);
    cut = nm;
}

// ---------------- score + top-k kernel ----------------
__global__ __launch_bounds__(256, 2)
void score_topk_kernel(const float* __restrict__ query,
                       const char* __restrict__ bprep,
                       const float* __restrict__ m2la,
                       const float* __restrict__ log_tau_p,
                       u64* __restrict__ cand)
{
    __shared__ __align__(16) short Bs[CH_BYTES / 2];   // 32 KB fragment buffer
    __shared__ __align__(16) float St[QT * SLD];       // 34.8 KB score tile / end scratch

    const int tid   = threadIdx.x;
    const int lane  = tid & 63;
    const int quad  = lane >> 4;
    const int mrow  = lane & 15;
    const int wv    = tid >> 6;
    const int qbase = blockIdx.y * QT;

    const float nhit = -0.5f * expf(-log_tau_p[0]);

    // ---- build persistent A fragments (hi+lo) in registers ----
    bf16x8 ahi[2][4], alo[2][4];
    #pragma unroll
    for (int mt = 0; mt < 2; ++mt) {
        const float* qrow = query + (size_t)(qbase + wv * 32 + mt * 16 + mrow) * DS;
        #pragma unroll
        for (int ks = 0; ks < 4; ++ks) {
            int kq = ks * 32 + quad * 8;
            int d0 = kq & 63;
            bool lin = kq >= 64;
            bf16x8 h, l;
            #pragma unroll
            for (int j = 0; j < 8; ++j) {
                float v = qrow[d0 + j];
                float x = lin ? (-2.0f * v) : (v * v);
                __bf16 hb = (__bf16)x;
                h[j] = hb;
                l[j] = (__bf16)(x - (float)hb);
            }
            ahi[mt][ks] = h; alo[mt][ks] = l;
        }
    }

    // ---- per-thread top-16 state (query = tid&127, half = tid>>7) ----
    float ts[16]; int ti[16];
    #pragma unroll
    for (int i = 0; i < 16; ++i) { ts[i] = -INFINITY; ti[i] = 0; }
    float cut = -INFINITY;
    const int qloc = tid & 127;
    const int half = tid >> 7;

    const char* BsB = (const char*)Bs;

    // ---- stage first chunk ----
    int c = blockIdx.x;
    {
        const char* src = bprep + (size_t)c * CH_BYTES;
        #pragma unroll
        for (int i = 0; i < 8; ++i) {
            int s = tid + i * 256;
            async_cp16(src + s * 16, (void*)(BsB + s * 16));
        }
    }
    __syncthreads();   // drains vmcnt -> Bs ready

    for (int it = 0; it < CHUNKS_PER_BLK; ++it) {
        const int nbase = c * BC;
        const int cn    = c + PCH;
        const bool more = (it + 1) < CHUNKS_PER_BLK;

        // m2/log-alpha loads for this chunk (consumed after B1; hidden under MFMA)
        float2 ml[4];
        #pragma unroll
        for (int nt = 0; nt < 4; ++nt)
            ml[nt] = *(const float2*)&m2la[(size_t)(nbase + nt * 16 + mrow) * 2];

        // ---- MFMA: 4 ntiles x 2 mtiles x 4 ksteps x 3 products ----
        f32x4 acc[2][4];
        #pragma unroll
        for (int nt = 0; nt < 4; ++nt) {
            bf16x8 bh[4], bl[4];
            #pragma unroll
            for (int ks = 0; ks < 4; ++ks) {
                bh[ks] = *(const bf16x8*)(BsB + nt * 4096 + ks * 1024 + lane * 16);
                bl[ks] = *(const bf16x8*)(BsB + SPLIT_OFF + nt * 4096 + ks * 1024 + lane * 16);
            }
            #pragma unroll
            for (int mt = 0; mt < 2; ++mt) {
                f32x4 a = {0.0f, 0.0f, 0.0f, 0.0f};
                #pragma unroll
                for (int ks = 0; ks < 4; ++ks) {
                    a = __builtin_amdgcn_mfma_f32_16x16x32_bf16(ahi[mt][ks], bh[ks], a, 0, 0, 0);
                    a = __builtin_amdgcn_mfma_f32_16x16x32_bf16(ahi[mt][ks], bl[ks], a, 0, 0, 0);
                    a = __builtin_amdgcn_mfma_f32_16x16x32_bf16(alo[mt][ks], bh[ks], a, 0, 0, 0);
                }
                acc[mt][nt] = a;
            }
        }
        __syncthreads();   // B1: all frag reads done; Bs reusable

        // prefetch next chunk (waits complete at B2's implicit vmcnt drain)
        if (more) {
            const char* src = bprep + (size_t)cn * CH_BYTES;
            #pragma unroll
            for (int i = 0; i < 8; ++i) {
                int s = tid + i * 256;
                async_cp16(src + s * 16, (void*)(BsB + s * 16));
            }
        }

        // ---- epilogue: log-score -> Stile ----
        #pragma unroll
        for (int mt = 0; mt < 2; ++mt)
            #pragma unroll
            for (int nt = 0; nt < 4; ++nt) {
                float m2 = ml[nt].x, la = ml[nt].y;
                #pragma unroll
                for (int reg = 0; reg < 4; ++reg) {
                    float sc = nhit * (acc[mt][nt][reg] + m2) + la;
                    St[(wv * 32 + mt * 16 + quad * 4 + reg) * SLD + nt * 16 + mrow] = sc;
                }
            }
        __syncthreads();   // B2: Stile ready

        // ---- scan my (query, half) stream: 32 blobs as 8 float4 ----
        {
            const float4* rowp = (const float4*)&St[qloc * SLD + half * 32];
            const int b0 = nbase + half * 32;
            for (int i = 0; i < 8; ++i) {
                float4 v = rowp[i];
                float m01 = fmaxf(v.x, v.y), m23 = fmaxf(v.z, v.w);
                if (fmaxf(m01, m23) > cut) {
                    int bb = b0 + i * 4;
                    if (v.x > cut) ins16(ts, ti, cut, v.x, bb);
                    if (v.y > cut) ins16(ts, ti, cut, v.y, bb + 1);
                    if (v.z > cut) ins16(ts, ti, cut, v.z, bb + 2);
                    if (v.w > cut) ins16(ts, ti, cut, v.w, bb + 3);
                }
            }
        }
        __syncthreads();   // B3: scans done (Stile free); prefetched Bs ready
        c = cn;
    }

    // ---- merge the two half-streams per query, write per-block top-16 ----
    u64* SK = (u64*)St;                 // [128][33] u64 = 33.8 KB (fits in St)
    #pragma unroll
    for (int i = 0; i < 16; ++i)
        SK[qloc * 33 + half * 16 + i] =
            ((u64)map_f32(ts[i]) << 32) | (u64)(0xFFFFFFFFu - (unsigned)ti[i]);
    __syncthreads();

    if (tid < QT) {
        u64* row = SK + tid * 33;
        u64* dst = cand + (size_t)(qbase + tid) * CPQ + blockIdx.x * KSEL;
        for (int r = 0; r < KSEL; ++r) {
            int bm = 0; u64 bv = row[0];
            #pragma unroll 4
            for (int j = 1; j < 32; ++j) { u64 v = row[j]; if (v > bv) { bv = v; bm = j; } }
            row[bm] = 0;
            dst[r] = bv;
        }
    }
}

// ---------------- global merge + exact recompute + compositing ----------------
__global__ __launch_bounds__(256)
void merge_composite_kernel(const float* __restrict__ query,
                            const float* __restrict__ mu,
                            const float* __restrict__ log_var,
                            const float* __restrict__ raw_alpha,
                            const float* __restrict__ features,
                            const float* __restrict__ log_tau_p,
                            const u64* __restrict__ cand,
                            float* __restrict__ out)
{
    const int q   = blockIdx.x;
    const int tid = threadIdx.x;
    const int wv = tid >> 6, lane = tid & 63;

    __shared__ u64   wmax[4];
    __shared__ int   sel[KSEL];
    __shared__ float w_sh[KSEL];
    __shared__ float mah[KSEL];
    __shared__ float alp[KSEL];

    u64 k[4];
    #pragma unroll
    for (int r = 0; r < 4; ++r) k[r] = cand[(size_t)q * CPQ + tid + r * 256];

    for (int r = 0; r < KSEL; ++r) {
        u64 m = k[0];
        #pragma unroll
        for (int j = 1; j < 4; ++j) if (k[j] > m) m = k[j];
        #pragma unroll
        for (int off = 32; off > 0; off >>= 1) {
            unsigned hi = __shfl_xor((unsigned)(m >> 32), off);
            unsigned lo = __shfl_xor((unsigned)(m & 0xFFFFFFFFu), off);
            u64 o = ((u64)hi << 32) | lo;
            if (o > m) m = o;
        }
        if (lane == 0) wmax[wv] = m;
        __syncthreads();
        u64 w = wmax[0];
        #pragma unroll
        for (int t = 1; t < 4; ++t) if (wmax[t] > w) w = wmax[t];
        if (tid == 0)
            sel[r] = (int)(0xFFFFFFFFu - (unsigned)(w & 0xFFFFFFFFull));
        #pragma unroll
        for (int j = 0; j < 4; ++j) if (k[j] == w) k[j] = 0ull;  // keys unique
        __syncthreads();
    }

    // exact mahal per selected blob (direct gathered form, like reference)
    for (int r = wv; r < KSEL; r += 4) {
        int bi = sel[r];
        float qd = query[(size_t)q * DS + lane];
        float mv = mu[(size_t)bi * DS + lane];
        float d  = qd - mv;
        float t  = d * d * expf(-log_var[(size_t)bi * DS + lane]);
        #pragma unroll
        for (int off = 32; off > 0; off >>= 1) t += __shfl_down(t, off);
        if (lane == 0) {
            mah[r] = t;
            alp[r] = 1.0f / (1.0f + expf(-raw_alpha[bi]));
        }
    }
    __syncthreads();

    if (tid == 0) {
        float tau = expf(log_tau_p[0]);
        float cap = 0.3f / 16.0f;
        float logT = 0.0f;
        for (int r = 0; r < KSEL; ++r) {
            float K   = expf(-0.5f * mah[r] / tau);
            float eff = fminf(alp[r] * K, cap);
            w_sh[r]   = eff * expf(logT);
            logT     += log1pf(-fminf(eff, 1.0f - 1e-6f));
        }
        out[(size_t)BQ * DF + q] = expf(logT);
    }
    __syncthreads();

    {
        float a = 0.0f;
        #pragma unroll
        for (int r = 0; r < KSEL; ++r)
            a += w_sh[r] * features[(size_t)sel[r] * DF + tid];
        out[(size_t)q * DF + tid] = a;
    }
}

// ---------------- launch ----------------
extern "C" void kernel_launch(void* const* d_in, const int* in_sizes, int n_in,
                              void* d_out, int out_size, void* d_ws, size_t ws_size,
                              hipStream_t stream)
{
    (void)in_sizes; (void)n_in; (void)out_size; (void)ws_size;
    const float* query     = (const float*)d_in[0];
    const float* mu        = (const float*)d_in[1];
    const float* log_var   = (const float*)d_in[2];
    const float* raw_alpha = (const float*)d_in[3];
    const float* features  = (const float*)d_in[4];
    const float* log_tau   = (const float*)d_in[5];
    float* out = (float*)d_out;

    // ws layout: Bprep 64 MB | m2la 1 MB | cand 8 MB
    char*  bprep = (char*)d_ws;
    float* m2la  = (float*)((char*)d_ws + (size_t)NCHUNK * CH_BYTES);
    u64*   cand  = (u64*)((char*)d_ws + (size_t)NCHUNK * CH_BYTES + (size_t)NB * 2 * 4);

    prep_b_kernel<<<(NCHUNK * 16 * 64) / 256 * 4 / 4, 256, 0, stream>>>(mu, log_var, bprep);
    // grid = 2^21/256 = 8192 blocks
    prep_m_kernel<<<NB / 4, 256, 0, stream>>>(mu, log_var, raw_alpha, m2la);

    dim3 g2(PCH, BQ / QT);
    score_topk_kernel<<<g2, 256, 0, stream>>>(query, bprep, m2la, log_tau, cand);

    merge_composite_kernel<<<BQ, 256, 0, stream>>>(query, mu, log_var, raw_alpha,
                                                   features, log_tau, cand, out);
}

// Round 4
// 663.356 us; speedup vs baseline: 7.1485x; 1.0873x over previous
//
#include <hip/hip_runtime.h>
#include <math.h>

// ---------------- problem constants ----------------
#define BQ    1024
#define NB    131072
#define DS    64
#define DF    256
#define KSEL  16

// ---------------- score kernel tiling ----------------
#define QT    128        // queries per block (4 waves x 32)
#define BC    64         // blobs per chunk
#define PCH   64         // chunk stripes (grid.x)
#define NCHUNK (NB / BC)             // 2048
#define CHUNKS_PER_BLK (NCHUNK/PCH)  // 32
#define CPQ   (PCH * KSEL)           // 1024 candidates per query
#define SLD   68                     // Stile leading dim (floats, 272B rows, 16B-aligned)

// Bprep layout per chunk: [split(2)][ntile(4)][kstep(4)][lane(64)][16B] = 32 KB
#define CH_BYTES   32768
#define SPLIT_OFF  16384

typedef __bf16 bf16x8 __attribute__((ext_vector_type(8)));
typedef float  f32x4  __attribute__((ext_vector_type(4)));
typedef unsigned long long u64;

__device__ __forceinline__ unsigned map_f32(float s) {
    unsigned u = __float_as_uint(s);
    return (u & 0x80000000u) ? ~u : (u | 0x80000000u);
}

__device__ __forceinline__ void async_cp16(const void* g, void* l) {
    __builtin_amdgcn_global_load_lds(
        (const __attribute__((address_space(1))) unsigned int*)g,
        (__attribute__((address_space(3))) unsigned int*)l, 16, 0, 0);
}

// ---------------- fused preprocess: fragments + m2 + log-alpha ----------------
// thread = (blob, dd): 8 consecutive d of one blob; computes iv once,
// emits hi/lo bf16 frags for BOTH rows (iv, mu*iv), partial m2 via shuffle.
__global__ __launch_bounds__(256)
void prep_kernel(const float* __restrict__ mu,
                 const float* __restrict__ log_var,
                 const float* __restrict__ raw_alpha,
                 char* __restrict__ bprep,
                 float* __restrict__ m2la)
{
    int gid  = blockIdx.x * 256 + threadIdx.x;   // NB*8 = 2^20 threads
    int blob = gid >> 3;
    int dd   = gid & 7;

    const float* mrow = mu      + (size_t)blob * DS + dd * 8;
    const float* vrow = log_var + (size_t)blob * DS + dd * 8;
    float4 ma = ((const float4*)mrow)[0], mb = ((const float4*)mrow)[1];
    float4 va = ((const float4*)vrow)[0], vb = ((const float4*)vrow)[1];
    float m[8] = {ma.x, ma.y, ma.z, ma.w, mb.x, mb.y, mb.z, mb.w};
    float lv[8] = {va.x, va.y, va.z, va.w, vb.x, vb.y, vb.z, vb.w};

    bf16x8 hiv, liv, hmv, lmv;
    float p = 0.0f;
    #pragma unroll
    for (int j = 0; j < 8; ++j) {
        float iv = __expf(-lv[j]);
        float mv = m[j] * iv;
        p += m[j] * mv;
        __bf16 h1 = (__bf16)iv;  hiv[j] = h1; liv[j] = (__bf16)(iv - (float)h1);
        __bf16 h2 = (__bf16)mv;  hmv[j] = h2; lmv[j] = (__bf16)(mv - (float)h2);
    }
    p += __shfl_xor(p, 1);
    p += __shfl_xor(p, 2);
    p += __shfl_xor(p, 4);

    int c  = blob >> 6;
    int nt = (blob >> 4) & 3;
    int bl = blob & 15;
    int lane  = (dd & 3) * 16 + bl;
    int ks_iv = dd >> 2;            // k = dd*8      (iv rows: k in [0,64))
    int ks_mv = 2 + (dd >> 2);      // k = 64+dd*8   (mu*iv rows)
    size_t b_iv = (size_t)c * CH_BYTES + nt * 4096 + ks_iv * 1024 + lane * 16;
    size_t b_mv = (size_t)c * CH_BYTES + nt * 4096 + ks_mv * 1024 + lane * 16;
    *(bf16x8*)(bprep + b_iv)             = hiv;
    *(bf16x8*)(bprep + b_iv + SPLIT_OFF) = liv;
    *(bf16x8*)(bprep + b_mv)             = hmv;
    *(bf16x8*)(bprep + b_mv + SPLIT_OFF) = lmv;

    if (dd == 0) {
        m2la[blob * 2]     = p;
        m2la[blob * 2 + 1] = -log1pf(__expf(-raw_alpha[blob]));  // log sigmoid
    }
}

// ---------------- register top-16 insertion (tree argmin, unsorted) ----------------
__device__ __forceinline__ void ins16(float (&ts)[16], int (&ti)[16],
                                      float& mymin, float s, int idx)
{
    float v0[8]; int j0[8];
    #pragma unroll
    for (int i = 0; i < 8; ++i) {
        bool b = ts[2*i+1] < ts[2*i];
        v0[i] = b ? ts[2*i+1] : ts[2*i];
        j0[i] = (i << 1) | (b ? 1 : 0);
    }
    float v1[4]; int j1[4];
    #pragma unroll
    for (int i = 0; i < 4; ++i) {
        bool b = v0[2*i+1] < v0[2*i];
        v1[i] = b ? v0[2*i+1] : v0[2*i];
        j1[i] = b ? j0[2*i+1] : j0[2*i];
    }
    float v2[2]; int j2[2];
    #pragma unroll
    for (int i = 0; i < 2; ++i) {
        bool b = v1[2*i+1] < v1[2*i];
        v2[i] = b ? v1[2*i+1] : v1[2*i];
        j2[i] = b ? j1[2*i+1] : j1[2*i];
    }
    int am = (v2[1] < v2[0]) ? j2[1] : j2[0];
    #pragma unroll
    for (int i = 0; i < 16; ++i) {
        bool b = (i == am);
        ts[i] = b ? s : ts[i];
        ti[i] = b ? idx : ti[i];
    }
    float n0[8];
    #pragma unroll
    for (int i = 0; i < 8; ++i) n0[i] = fminf(ts[2*i], ts[2*i+1]);
    float n1[4];
    #pragma unroll
    for (int i = 0; i < 4; ++i) n1[i] = fminf(n0[2*i], n0[2*i+1]);
    mymin = fminf(fminf(n1[0], n1[1]), fminf(n1[2], n1[3]));
}

// ---------------- score + top-k kernel ----------------
__global__ __launch_bounds__(256, 2)
void score_topk_kernel(const float* __restrict__ query,
                       const char* __restrict__ bprep,
                       const float* __restrict__ m2la,
                       const float* __restrict__ log_tau_p,
                       u64* __restrict__ cand)
{
    __shared__ __align__(16) short Bs[CH_BYTES / 2];   // 32 KB fragment buffer
    __shared__ __align__(16) float St[QT * SLD];       // 34.8 KB score tile / end scratch
    __shared__ float scv[2 * QT];                      // published half-stream cutoffs

    const int tid   = threadIdx.x;
    const int lane  = tid & 63;
    const int quad  = lane >> 4;
    const int mrow  = lane & 15;
    const int wv    = tid >> 6;
    const int qbase = blockIdx.y * QT;

    const float nhit = -0.5f * expf(-log_tau_p[0]);

    // ---- build persistent A fragments (hi+lo) in registers ----
    bf16x8 ahi[2][4], alo[2][4];
    #pragma unroll
    for (int mt = 0; mt < 2; ++mt) {
        const float* qrow = query + (size_t)(qbase + wv * 32 + mt * 16 + mrow) * DS;
        #pragma unroll
        for (int ks = 0; ks < 4; ++ks) {
            int kq = ks * 32 + quad * 8;
            int d0 = kq & 63;
            bool lin = kq >= 64;
            bf16x8 h, l;
            #pragma unroll
            for (int j = 0; j < 8; ++j) {
                float v = qrow[d0 + j];
                float x = lin ? (-2.0f * v) : (v * v);
                __bf16 hb = (__bf16)x;
                h[j] = hb;
                l[j] = (__bf16)(x - (float)hb);
            }
            ahi[mt][ks] = h; alo[mt][ks] = l;
        }
    }

    // ---- per-thread top-16 state (query = tid&127, half = tid>>7) ----
    float ts[16]; int ti[16];
    #pragma unroll
    for (int i = 0; i < 16; ++i) { ts[i] = -INFINITY; ti[i] = 0; }
    float mymin = -INFINITY;
    const int qloc = tid & 127;
    const int half = tid >> 7;
    if (tid < 2 * QT) scv[tid] = -INFINITY;

    const char* BsB = (const char*)Bs;

    // ---- stage first chunk ----
    int c = blockIdx.x;
    {
        const char* src = bprep + (size_t)c * CH_BYTES;
        #pragma unroll
        for (int i = 0; i < 8; ++i) {
            int s = tid + i * 256;
            async_cp16(src + s * 16, (void*)(BsB + s * 16));
        }
    }
    __syncthreads();   // drains vmcnt -> Bs ready; scv init visible

    for (int it = 0; it < CHUNKS_PER_BLK; ++it) {
        const int nbase = c * BC;
        const int cn    = c + PCH;
        const bool more = (it + 1) < CHUNKS_PER_BLK;

        float2 ml[4];
        #pragma unroll
        for (int nt = 0; nt < 4; ++nt)
            ml[nt] = *(const float2*)&m2la[(size_t)(nbase + nt * 16 + mrow) * 2];

        // ---- MFMA: 4 ntiles x 2 mtiles x 4 ksteps x 3 products ----
        f32x4 acc[2][4];
        #pragma unroll
        for (int nt = 0; nt < 4; ++nt) {
            bf16x8 bh[4], bl[4];
            #pragma unroll
            for (int ks = 0; ks < 4; ++ks) {
                bh[ks] = *(const bf16x8*)(BsB + nt * 4096 + ks * 1024 + lane * 16);
                bl[ks] = *(const bf16x8*)(BsB + SPLIT_OFF + nt * 4096 + ks * 1024 + lane * 16);
            }
            #pragma unroll
            for (int mt = 0; mt < 2; ++mt) {
                f32x4 a = {0.0f, 0.0f, 0.0f, 0.0f};
                #pragma unroll
                for (int ks = 0; ks < 4; ++ks) {
                    a = __builtin_amdgcn_mfma_f32_16x16x32_bf16(ahi[mt][ks], bh[ks], a, 0, 0, 0);
                    a = __builtin_amdgcn_mfma_f32_16x16x32_bf16(ahi[mt][ks], bl[ks], a, 0, 0, 0);
                    a = __builtin_amdgcn_mfma_f32_16x16x32_bf16(alo[mt][ks], bh[ks], a, 0, 0, 0);
                }
                acc[mt][nt] = a;
            }
        }
        __syncthreads();   // B1: frag reads done; Bs reusable

        if (more) {
            const char* src = bprep + (size_t)cn * CH_BYTES;
            #pragma unroll
            for (int i = 0; i < 8; ++i) {
                int s = tid + i * 256;
                async_cp16(src + s * 16, (void*)(BsB + s * 16));
            }
        }

        // ---- epilogue: log-score -> Stile ----
        #pragma unroll
        for (int mt = 0; mt < 2; ++mt)
            #pragma unroll
            for (int nt = 0; nt < 4; ++nt) {
                float m2 = ml[nt].x, la = ml[nt].y;
                #pragma unroll
                for (int reg = 0; reg < 4; ++reg) {
                    float sc = nhit * (acc[mt][nt][reg] + m2) + la;
                    St[(wv * 32 + mt * 16 + quad * 4 + reg) * SLD + nt * 16 + mrow] = sc;
                }
            }
        __syncthreads();   // B2: Stile ready

        // ---- scan: branchless screen + lane-local survivor iteration ----
        {
            volatile float* vsc = scv;
            float ocut = vsc[(half ^ 1) * QT + qloc];
            float cut = fmaxf(mymin, ocut);
            const float* rowp = &St[qloc * SLD + half * 32];
            unsigned gm = 0u;
            #pragma unroll
            for (int i = 0; i < 8; ++i) {
                float4 v = ((const float4*)rowp)[i];
                float mx = fmaxf(fmaxf(v.x, v.y), fmaxf(v.z, v.w));
                if (mx > cut) gm |= (1u << i);
            }
            while (__any(gm != 0u)) {
                if (gm) {
                    int i = __ffs(gm) - 1;
                    gm &= gm - 1u;
                    float4 v = ((const float4*)rowp)[i];
                    int b0 = nbase + half * 32 + i * 4;
                    if (v.x > cut) { ins16(ts, ti, mymin, v.x, b0);     cut = fmaxf(mymin, ocut); }
                    if (v.y > cut) { ins16(ts, ti, mymin, v.y, b0 + 1); cut = fmaxf(mymin, ocut); }
                    if (v.z > cut) { ins16(ts, ti, mymin, v.z, b0 + 2); cut = fmaxf(mymin, ocut); }
                    if (v.w > cut) { ins16(ts, ti, mymin, v.w, b0 + 3); cut = fmaxf(mymin, ocut); }
                }
            }
            vsc[half * QT + qloc] = mymin;   // publish (monotone; races benign)
        }
        __syncthreads();   // B3: scans done (Stile free); prefetched Bs ready
        c = cn;
    }
    __syncthreads();

    // ---- merge the two half-streams per query, write per-block top-16 ----
    u64* SK = (u64*)St;                 // [128][33] u64 = 33.8 KB (fits in St)
    #pragma unroll
    for (int i = 0; i < 16; ++i)
        SK[qloc * 33 + half * 16 + i] =
            ((u64)map_f32(ts[i]) << 32) | (u64)(0xFFFFFFFFu - (unsigned)ti[i]);
    __syncthreads();

    if (tid < QT) {
        u64* row = SK + tid * 33;
        u64* dst = cand + (size_t)(qbase + tid) * CPQ + blockIdx.x * KSEL;
        for (int r = 0; r < KSEL; ++r) {
            int bm = 0; u64 bv = row[0];
            #pragma unroll 4
            for (int j = 1; j < 32; ++j) { u64 v = row[j]; if (v > bv) { bv = v; bm = j; } }
            row[bm] = 0;
            dst[r] = bv;
        }
    }
}

// ---------------- global merge + exact recompute + compositing ----------------
__global__ __launch_bounds__(256)
void merge_composite_kernel(const float* __restrict__ query,
                            const float* __restrict__ mu,
                            const float* __restrict__ log_var,
                            const float* __restrict__ raw_alpha,
                            const float* __restrict__ features,
                            const float* __restrict__ log_tau_p,
                            const u64* __restrict__ cand,
                            float* __restrict__ out)
{
    const int q   = blockIdx.x;
    const int tid = threadIdx.x;
    const int wv = tid >> 6, lane = tid & 63;

    __shared__ u64   wtop[4 * KSEL];
    __shared__ int   sel[KSEL];
    __shared__ float w_sh[KSEL];
    __shared__ float mah[KSEL];
    __shared__ float alp[KSEL];

    // 1024 keys: each wave owns 256 contiguous (4 per lane)
    u64 k[4];
    #pragma unroll
    for (int r = 0; r < 4; ++r)
        k[r] = cand[(size_t)q * CPQ + wv * 256 + r * 64 + lane];

    // wave-local top-16 (no barriers)
    for (int r = 0; r < KSEL; ++r) {
        u64 m = k[0];
        #pragma unroll
        for (int j = 1; j < 4; ++j) if (k[j] > m) m = k[j];
        #pragma unroll
        for (int off = 32; off > 0; off >>= 1) {
            unsigned hi = __shfl_xor((unsigned)(m >> 32), off);
            unsigned lo = __shfl_xor((unsigned)(m & 0xFFFFFFFFu), off);
            u64 o = ((u64)hi << 32) | lo;
            if (o > m) m = o;
        }
        if (lane == 0) wtop[wv * KSEL + r] = m;
        #pragma unroll
        for (int j = 0; j < 4; ++j) if (k[j] == m) k[j] = 0ull;  // keys unique
    }
    __syncthreads();

    // wave 0: merge 64 -> 16 (shuffle argmax rounds)
    if (wv == 0) {
        u64 kk = wtop[lane];
        for (int r = 0; r < KSEL; ++r) {
            u64 m = kk;
            #pragma unroll
            for (int off = 32; off > 0; off >>= 1) {
                unsigned hi = __shfl_xor((unsigned)(m >> 32), off);
                unsigned lo = __shfl_xor((unsigned)(m & 0xFFFFFFFFu), off);
                u64 o = ((u64)hi << 32) | lo;
                if (o > m) m = o;
            }
            if (kk == m) kk = 0ull;
            if (lane == 0)
                sel[r] = (int)(0xFFFFFFFFu - (unsigned)(m & 0xFFFFFFFFull));
        }
    }
    __syncthreads();

    // exact mahal per selected blob (direct gathered form, like reference)
    for (int r = wv; r < KSEL; r += 4) {
        int bi = sel[r];
        float qd = query[(size_t)q * DS + lane];
        float mv = mu[(size_t)bi * DS + lane];
        float d  = qd - mv;
        float t  = d * d * expf(-log_var[(size_t)bi * DS + lane]);
        #pragma unroll
        for (int off = 32; off > 0; off >>= 1) t += __shfl_down(t, off);
        if (lane == 0) {
            mah[r] = t;
            alp[r] = 1.0f / (1.0f + expf(-raw_alpha[bi]));
        }
    }
    __syncthreads();

    if (tid == 0) {
        float tau = expf(log_tau_p[0]);
        float cap = 0.3f / 16.0f;
        float logT = 0.0f;
        for (int r = 0; r < KSEL; ++r) {
            float K   = expf(-0.5f * mah[r] / tau);
            float eff = fminf(alp[r] * K, cap);
            w_sh[r]   = eff * expf(logT);
            logT     += log1pf(-fminf(eff, 1.0f - 1e-6f));
        }
        out[(size_t)BQ * DF + q] = expf(logT);
    }
    __syncthreads();

    {
        float a = 0.0f;
        #pragma unroll
        for (int r = 0; r < KSEL; ++r)
            a += w_sh[r] * features[(size_t)sel[r] * DF + tid];
        out[(size_t)q * DF + tid] = a;
    }
}

// ---------------- launch ----------------
extern "C" void kernel_launch(void* const* d_in, const int* in_sizes, int n_in,
                              void* d_out, int out_size, void* d_ws, size_t ws_size,
                              hipStream_t stream)
{
    (void)in_sizes; (void)n_in; (void)out_size; (void)ws_size;
    const float* query     = (const float*)d_in[0];
    const float* mu        = (const float*)d_in[1];
    const float* log_var   = (const float*)d_in[2];
    const float* raw_alpha = (const float*)d_in[3];
    const float* features  = (const float*)d_in[4];
    const float* log_tau   = (const float*)d_in[5];
    float* out = (float*)d_out;

    // ws layout: Bprep 64 MB | m2la 1 MB | cand 8 MB
    char*  bprep = (char*)d_ws;
    float* m2la  = (float*)((char*)d_ws + (size_t)NCHUNK * CH_BYTES);
    u64*   cand  = (u64*)((char*)d_ws + (size_t)NCHUNK * CH_BYTES + (size_t)NB * 2 * 4);

    prep_kernel<<<(NB * 8) / 256, 256, 0, stream>>>(mu, log_var, raw_alpha, bprep, m2la);

    dim3 g2(PCH, BQ / QT);
    score_topk_kernel<<<g2, 256, 0, stream>>>(query, bprep, m2la, log_tau, cand);

    merge_composite_kernel<<<BQ, 256, 0, stream>>>(query, mu, log_var, raw_alpha,
                                                   features, log_tau, cand, out);
}